// Round 19
// baseline (162.212 us; speedup 1.0000x reference)
//
#include <hip/hip_runtime.h>

#define S_LEN 2048
#define EDIM  1024
#define HEADS 16
#define DHEAD 64

typedef __attribute__((ext_vector_type(8))) short bf16x8;
typedef __attribute__((ext_vector_type(4))) short short4v;
typedef __attribute__((ext_vector_type(4))) float f32x4;

__device__ inline unsigned short f2bf(float f) {
    unsigned int u = __float_as_uint(f);
    unsigned int r = (u + 0x7FFFu + ((u >> 16) & 1u)) >> 16;
    return (unsigned short)r;
}
__device__ inline float bf2f(unsigned short b) {
    return __uint_as_float(((unsigned int)b) << 16);
}
__device__ inline void load_lds16(const void* g, void* l) {
    __builtin_amdgcn_global_load_lds(
        (const __attribute__((address_space(1))) unsigned int*)g,
        (__attribute__((address_space(3))) unsigned int*)l, 16, 0, 0);
}

// ---------------- X fp32 -> bf16 ----------------
__global__ void k_convert_x(const float* __restrict__ x, short* __restrict__ xb, int n4) {
    int i = blockIdx.x * blockDim.x + threadIdx.x;
    if (i >= n4) return;
    f32x4 v = ((const f32x4*)x)[i];
    short4v o;
    o[0] = (short)f2bf(v[0]); o[1] = (short)f2bf(v[1]);
    o[2] = (short)f2bf(v[2]); o[3] = (short)f2bf(v[3]);
    ((short4v*)xb)[i] = o;
}

// ---------------- tiled transpose + fp32->bf16: in[R][C] -> out[C][R], batched over z ----------------
__global__ void k_transpose_cvt(const float* __restrict__ in, short* __restrict__ out, int R, int C) {
    __shared__ float tile[32][33];
    const int b = blockIdx.z;
    in  += (size_t)b * R * C;
    out += (size_t)b * R * C;
    const int c0 = blockIdx.x * 32, r0 = blockIdx.y * 32;
    #pragma unroll
    for (int yy = 0; yy < 4; ++yy) {
        int r = r0 + threadIdx.y + yy * 8, c = c0 + threadIdx.x;
        tile[threadIdx.y + yy * 8][threadIdx.x] = (r < R && c < C) ? in[(size_t)r * C + c] : 0.f;
    }
    __syncthreads();
    #pragma unroll
    for (int yy = 0; yy < 4; ++yy) {
        int c = c0 + threadIdx.y + yy * 8, r = r0 + threadIdx.x;
        if (c < C && r < R) out[(size_t)c * R + r] = (short)f2bf(tile[threadIdx.x][threadIdx.y + yy * 8]);
    }
}

// ---------------- LDS-staged MFMA GEMM core (m97 structure, NW-wave generalized) ----------------
template<int BM, int BN, int WR, int WC>
__device__ inline void gemm_core(const char* Ag, int ldaB, const char* Bg, int ldbB,
                                 int K, char* sA, char* sB, f32x4* acc) {
    constexpr int NW = WR * WC;
    constexpr int FM = BM / (WR * 16), FN = BN / (WC * 16);
    constexpr int CA = (BM * 128) / (1024 * NW);   // A 1KB-chunks per wave
    constexpr int CB = (BN * 128) / (1024 * NW);   // B 1KB-chunks per wave
    const int lane = threadIdx.x & 63, wave = threadIdx.x >> 6;
    const int rl = lane & 15, g = lane >> 4;
    const int wrow = (wave / WC) * (BM / WR);
    const int wcol = (wave % WC) * (BN / WC);
    const int lr = lane >> 3;                 // row within 8-row chunk
    const int lc = ((lane & 7) ^ lr) << 4;    // inverse-swizzled 16B slot

    for (int t = 0; t < K / 64; ++t) {
        __syncthreads();
        #pragma unroll
        for (int i = 0; i < CA; ++i) {
            const int c = i * NW + wave;      // chunk c covers rows [8c, 8c+8)
            load_lds16(Ag + (size_t)(c * 8 + lr) * ldaB + t * 128 + lc, sA + c * 1024);
        }
        #pragma unroll
        for (int i = 0; i < CB; ++i) {
            const int c = i * NW + wave;
            load_lds16(Bg + (size_t)(c * 8 + lr) * ldbB + t * 128 + lc, sB + c * 1024);
        }
        __syncthreads();
        #pragma unroll
        for (int kk = 0; kk < 2; ++kk) {
            bf16x8 af[FM], bf[FN];
            #pragma unroll
            for (int f = 0; f < FM; ++f) {
                const int r = wrow + f * 16 + rl;
                af[f] = *(const bf16x8*)(sA + r * 128 + (((kk * 4 + g) ^ (r & 7)) << 4));
            }
            #pragma unroll
            for (int j = 0; j < FN; ++j) {
                const int r = wcol + j * 16 + rl;
                bf[j] = *(const bf16x8*)(sB + r * 128 + (((kk * 4 + g) ^ (r & 7)) << 4));
            }
            #pragma unroll
            for (int f = 0; f < FM; ++f)
                #pragma unroll
                for (int j = 0; j < FN; ++j)
                    acc[f * FN + j] = __builtin_amdgcn_mfma_f32_16x16x32_bf16(af[f], bf[j], acc[f * FN + j], 0, 0, 0);
        }
    }
}

// ---------------- QKV projection GEMM: 128x128 tiles, 8 waves (2M x 4N) ----------------
__global__ __launch_bounds__(512) void k_gemm_qkv(
        const short* __restrict__ Xb,
        const short* __restrict__ WqT, const short* __restrict__ WkT, const short* __restrict__ WvT,
        const float* __restrict__ bq, const float* __restrict__ bk, const float* __restrict__ bv,
        short* __restrict__ Qh, short* __restrict__ Kh, short* __restrict__ Vt) {
    __shared__ __align__(16) char sA[16384], sB[16384];
    int id = blockIdx.x;
    id = (id & 7) * 80 + (id >> 3);           // XCD-contiguous chunks
    const int mbase = (id % 16) * 128;
    const int y = id / 16;

    const short* Bt; const float* bias; int nbase; int which;
    if (y < 16)      { which = 0; Bt = WqT; bias = bq; nbase = y * 128; }
    else if (y < 32) { which = 1; Bt = WkT; bias = bk; nbase = (y - 16) * 128; }
    else             { which = 2; Bt = WvT; bias = bv; nbase = (y - 32) * 128; }

    f32x4 acc[8];
    #pragma unroll
    for (int i = 0; i < 8; ++i) acc[i] = (f32x4){0.f, 0.f, 0.f, 0.f};

    gemm_core<128, 128, 2, 4>((const char*)Xb + (size_t)mbase * 2048, 2048,
                              (const char*)Bt + (size_t)nbase * 2048, 2048,
                              EDIM, sA, sB, acc);

    const int lane = threadIdx.x & 63, wave = threadIdx.x >> 6;
    const int wr = (wave >> 2) * 64, wc = (wave & 3) * 32;
    const int rl = lane & 15, g = lane >> 4;
    const float qscale = 0.125f * 1.44269504088896f;
    #pragma unroll
    for (int i = 0; i < 4; ++i)
        #pragma unroll
        for (int j = 0; j < 2; ++j)
            #pragma unroll
            for (int jj = 0; jj < 4; ++jj) {
                int s = mbase + wr + i * 16 + g * 4 + jj;
                int n = nbase + wc + j * 16 + rl;
                float v = acc[i * 2 + j][jj] + bias[n];
                if (which == 0) v *= qscale;
                short b16 = (short)f2bf(v);
                if (which == 0)      Qh[((size_t)(n >> 7) * S_LEN + s) * 128 + (n & 127)] = b16;
                else if (which == 1) Kh[((size_t)(n >> 7) * S_LEN + s) * 128 + (n & 127)] = b16;
                else                 Vt[(size_t)n * S_LEN + s] = b16;
            }
}

// ---------------- differential flash attention, v15: T4 counted-vmcnt + 4-buffer K pipeline ----------------
// v14 numerics exactly (KVBLK=32, fixed MFIX shift, ones-MFMA row sums, 2-way
// kv-split, V from global, P packed-pair [16 q][128B] rows, 3-phase p-fission).
// Sync change: __syncthreads (vmcnt(0) drain!) replaced by s_waitcnt vmcnt(2)
// + raw s_barrier; K is 4-buffered with a 2-deep prefetch (STAGE(i+2)), so the
// loads needed next iter were issued a FULL iteration ago. vf (global V) loads
// are issued before STAGE so the compiler's vf-consumption wait is vmcnt(2),
// never draining the in-flight prefetch. LDS = 2 kvg x 4 bufs x 8KB + 8x2KB P
// = 80KB -> 2 blocks/CU.
__global__ __launch_bounds__(512, 4) void k_attn(
        const short* __restrict__ Qh, const short* __restrict__ Kh,
        const short* __restrict__ Vt, const float* __restrict__ lam_p,
        short* __restrict__ Ocat) {
    __shared__ __align__(16) char smem[81920];

    const int lane = threadIdx.x & 63, wave = threadIdx.x >> 6;
    const int rl = lane & 15, g = lane >> 4;
    const int qw = wave & 3, kvg = wave >> 2;
    const int h = blockIdx.y;
    const int qbase = blockIdx.x * 64 + qw * 16;
    const int kx = rl & 7;              // K-row swizzle key (256B rows)
    const int swz = (rl & 7) << 4;      // P-row swizzle key (128B rows)
    const float MFIX = 6.0f;            // fixed exp2-domain shift

    char* Kg0 = smem + kvg * 32768;            // 4 bufs x 8KB: [32 kv][256B]
    char* Pw  = smem + 65536 + wave * 2048;    // [16 q][128B] = {p0 64B | p1 64B} swizzled

    const char* Kgb = (const char*)(Kh + (size_t)h * S_LEN * 128);
    const char* Vgb = (const char*)(Vt + (size_t)h * DHEAD * S_LEN);
    const short* Qp = Qh + (size_t)h * S_LEN * 128;

    const int kc0 = qw * 2, kc1 = qw * 2 + 1;
    const int kofs0 = (lane >> 4) * 256 + (((lane & 15) ^ (lane >> 4)) << 4);
    const int kofs1 = (lane >> 4) * 256 + (((lane & 15) ^ ((lane >> 4) + 4)) << 4);

    auto STAGE = [&](int b, int it) {
        const size_t kv0 = (size_t)(kvg * 1024 + it * 32);
        char* kb = Kg0 + b * 8192;
        load_lds16(Kgb + (kv0 + (size_t)kc0 * 4) * 256 + kofs0, kb + kc0 * 1024);
        load_lds16(Kgb + (kv0 + (size_t)kc1 * 4) * 256 + kofs1, kb + kc1 * 1024);
    };

    // prologue: qf loads first (oldest), then 2-deep K prefetch
    bf16x8 qf[2][2];
    #pragma unroll
    for (int p = 0; p < 2; ++p)
        #pragma unroll
        for (int kc = 0; kc < 2; ++kc)
            qf[p][kc] = *(const bf16x8*)&Qp[(size_t)(qbase + rl) * 128 + p * 64 + kc * 32 + g * 8];
    STAGE(0, 0);
    STAGE(1, 1);

    bf16x8 ones;
    #pragma unroll
    for (int i = 0; i < 8; ++i) ones[i] = (short)0x3F80;   // bf16 1.0

    f32x4 acc[2][4], accL[2];
    #pragma unroll
    for (int p = 0; p < 2; ++p) {
        #pragma unroll
        for (int t = 0; t < 4; ++t) acc[p][t] = (f32x4){0.f, 0.f, 0.f, 0.f};
        accL[p] = (f32x4){0.f, 0.f, 0.f, 0.f};
    }

    // drain qf + STAGE(0); leave STAGE(1) in flight
    asm volatile("s_waitcnt vmcnt(2)" ::: "memory");
    __builtin_amdgcn_s_barrier();
    __builtin_amdgcn_sched_barrier(0);

    const int NIT = 1024 / 32;
    for (int it = 0; it < NIT; ++it) {
        const char* kb = Kg0 + (it & 3) * 8192;
        const size_t kv0 = (size_t)(kvg * 1024 + it * 32);

        // ---- V fragments from global, issued BEFORE the stage (older in vmcnt order) ----
        bf16x8 vf[4];
        #pragma unroll
        for (int t = 0; t < 4; ++t)
            vf[t] = *(const bf16x8*)(Vgb + (size_t)(t * 16 + rl) * 4096 + (kv0 + g * 8) * 2);
        __builtin_amdgcn_sched_barrier(0);

        // ---- 2-deep prefetch: stage tile it+2 into buffer (it+2)&3 ----
        if (it + 2 < NIT) STAGE((it + 2) & 3, it + 2);
        __builtin_amdgcn_sched_barrier(0);

        // ---- phase 1: QK^T for BOTH p (swapped mfma(K,Q); exp2 domain) ----
        f32x4 sc[2][2];
        #pragma unroll
        for (int p = 0; p < 2; ++p)
            #pragma unroll
            for (int t = 0; t < 2; ++t) {
                f32x4 z = (f32x4){0.f, 0.f, 0.f, 0.f};
                #pragma unroll
                for (int kc = 0; kc < 2; ++kc) {
                    bf16x8 kf = *(const bf16x8*)(kb + t * 4096 + rl * 256 + (((p * 8 + kc * 4 + g) ^ kx) << 4));
                    z = __builtin_amdgcn_mfma_f32_16x16x32_bf16(kf, qf[p][kc], z, 0, 0, 0);
                }
                sc[p][t] = z;
            }

        // ---- phase 2: P = exp2(S - MFIX) for BOTH p (disjoint 64B halves) ----
        #pragma unroll
        for (int p = 0; p < 2; ++p)
            #pragma unroll
            for (int t = 0; t < 2; ++t)
                #pragma unroll
                for (int jjp = 0; jjp < 4; jjp += 2) {
                    float e0 = exp2f(sc[p][t][jjp]     - MFIX);
                    float e1 = exp2f(sc[p][t][jjp + 1] - MFIX);
                    unsigned u;
                    asm("v_cvt_pk_bf16_f32 %0, %1, %2" : "=v"(u) : "v"(e0), "v"(e1));
                    *(unsigned*)(Pw + rl * 128 + ((p * 64 + (t * 16 + g * 4 + jjp) * 2) ^ swz)) = u;
                }

        // ---- phase 3: pa reads + PV / ones MFMAs for BOTH p ----
        bf16x8 pa0 = *(const bf16x8*)(Pw + rl * 128 + ((0 * 64 + g * 16) ^ swz));
        bf16x8 pa1 = *(const bf16x8*)(Pw + rl * 128 + ((1 * 64 + g * 16) ^ swz));
        accL[0] = __builtin_amdgcn_mfma_f32_16x16x32_bf16(pa0, ones, accL[0], 0, 0, 0);
        accL[1] = __builtin_amdgcn_mfma_f32_16x16x32_bf16(pa1, ones, accL[1], 0, 0, 0);
        #pragma unroll
        for (int t = 0; t < 4; ++t) {
            acc[0][t] = __builtin_amdgcn_mfma_f32_16x16x32_bf16(pa0, vf[t], acc[0][t], 0, 0, 0);
            acc[1][t] = __builtin_amdgcn_mfma_f32_16x16x32_bf16(pa1, vf[t], acc[1][t], 0, 0, 0);
        }

        // ---- counted-vmcnt barrier: never drain the 2-deep prefetch (T4) ----
        asm volatile("s_waitcnt vmcnt(2)" ::: "memory");
        __builtin_amdgcn_s_barrier();
        __builtin_amdgcn_sched_barrier(0);
    }

    // ---- exchange partials through LDS (K/P regions dead after final barrier) ----
    {
        unsigned short* Xw = (unsigned short*)(smem + wave * 4096);  // [2][16][64] bf16
        float* ML = (float*)(smem + 32768);                          // [8w][2p][16 q] l only
        #pragma unroll
        for (int p = 0; p < 2; ++p) {
            #pragma unroll
            for (int t = 0; t < 4; ++t)
                #pragma unroll
                for (int jj = 0; jj < 4; ++jj)
                    Xw[p * 1024 + (g * 4 + jj) * 64 + t * 16 + rl] = f2bf(acc[p][t][jj]);
            if (rl == 0) {
                #pragma unroll
                for (int jj = 0; jj < 4; ++jj)
                    ML[(wave * 2 + p) * 16 + g * 4 + jj] = accL[p][jj];
            }
        }
    }
    __syncthreads();

    // ---- combine the 2 kv-group partials ----
    {
        const int q = threadIdx.x >> 3, d0 = (threadIdx.x & 7) * 8;
        const int q15 = q & 15, wa = q >> 4, wb = (q >> 4) + 4;
        const float* ML = (const float*)(smem + 32768);
        const float lam = lam_p[0];
        float res[2][8];
        float invL[2];
        #pragma unroll
        for (int p = 0; p < 2; ++p) {
            float la = ML[(wa * 2 + p) * 16 + q15];
            float lb = ML[(wb * 2 + p) * 16 + q15];
            invL[p] = 1.0f / (la + lb);
            const unsigned short* xa = (const unsigned short*)(smem + wa * 4096 + p * 2048 + q15 * 128 + d0 * 2);
            const unsigned short* xb = (const unsigned short*)(smem + wb * 4096 + p * 2048 + q15 * 128 + d0 * 2);
            #pragma unroll
            for (int k = 0; k < 8; ++k)
                res[p][k] = bf2f(xa[k]) + bf2f(xb[k]);
        }
        bf16x8 ov;
        #pragma unroll
        for (int k = 0; k < 8; ++k)
            ov[k] = (short)f2bf(res[0][k] * invL[0] - lam * res[1][k] * invL[1]);
        *(bf16x8*)&Ocat[(size_t)(blockIdx.x * 64 + q) * 1024 + h * 64 + d0] = ov;
    }
}

// ---------------- output projection GEMM: 64x128 tiles, 8 waves (2M x 4N) ----------------
__global__ __launch_bounds__(512) void k_gemm_out(
        const short* __restrict__ Ocat, const short* __restrict__ WoT,
        const float* __restrict__ bo, float* __restrict__ Yws) {
    __shared__ __align__(16) char sA[8192], sB[16384];
    int id = blockIdx.x;
    id = (id & 7) * 32 + (id >> 3);
    const int mbase = (id % 32) * 64;
    const int nbase = (id / 32) * 128;

    f32x4 acc[4];
    #pragma unroll
    for (int i = 0; i < 4; ++i) acc[i] = (f32x4){0.f, 0.f, 0.f, 0.f};

    gemm_core<64, 128, 2, 4>((const char*)Ocat + (size_t)mbase * 2048, 2048,
                             (const char*)WoT + (size_t)nbase * 2048, 2048,
                             1024, sA, sB, acc);

    const int lane = threadIdx.x & 63, wave = threadIdx.x >> 6;
    const int wr = (wave >> 2) * 32, wc = (wave & 3) * 32;
    const int rl = lane & 15, g = lane >> 4;
    #pragma unroll
    for (int f = 0; f < 2; ++f)
        #pragma unroll
        for (int j = 0; j < 2; ++j)
            #pragma unroll
            for (int jj = 0; jj < 4; ++jj) {
                int s = mbase + wr + f * 16 + g * 4 + jj;
                int e = nbase + wc + j * 16 + rl;
                Yws[(size_t)s * 1024 + e] = acc[f * 2 + j][jj] + bo[e];
            }
}

// ---------------- LayerNorm + final scale ----------------
__global__ __launch_bounds__(256) void k_ln(
        const float* __restrict__ Yws, const float* __restrict__ gamma,
        const float* __restrict__ beta, float* __restrict__ out) {
    const int s = blockIdx.x;
    const int tid = threadIdx.x;
    f32x4 y = ((const f32x4*)(Yws + (size_t)s * 1024))[tid];
    float sum = y[0] + y[1] + y[2] + y[3];
    float sq  = y[0]*y[0] + y[1]*y[1] + y[2]*y[2] + y[3]*y[3];
    #pragma unroll
    for (int off = 1; off < 64; off <<= 1) {
        sum += __shfl_xor(sum, off, 64);
        sq  += __shfl_xor(sq,  off, 64);
    }
    __shared__ float ls[2][4];
    const int wave = tid >> 6, lane = tid & 63;
    if (lane == 0) { ls[0][wave] = sum; ls[1][wave] = sq; }
    __syncthreads();
    sum = ls[0][0] + ls[0][1] + ls[0][2] + ls[0][3];
    sq  = ls[1][0] + ls[1][1] + ls[1][2] + ls[1][3];
    const float mu = sum * (1.f / 1024.f);
    const float var = sq * (1.f / 1024.f) - mu * mu;
    const float rstd = rsqrtf(var + 1e-5f);
    f32x4 gg = ((const f32x4*)gamma)[tid];
    f32x4 bb = ((const f32x4*)beta)[tid];
    f32x4 o;
    #pragma unroll
    for (int k = 0; k < 4; ++k)
        o[k] = ((y[k] - mu) * rstd * gg[k] + bb[k]) * 0.2f;
    ((f32x4*)(out + (size_t)s * 1024))[tid] = o;
}

extern "C" void kernel_launch(void* const* d_in, const int* in_sizes, int n_in,
                              void* d_out, int out_size, void* d_ws, size_t ws_size,
                              hipStream_t stream) {
    const float* X     = (const float*)d_in[0];
    const float* Wq    = (const float*)d_in[1];
    const float* bq    = (const float*)d_in[2];
    const float* Wk    = (const float*)d_in[3];
    const float* bk    = (const float*)d_in[4];
    const float* Wv    = (const float*)d_in[5];
    const float* bv    = (const float*)d_in[6];
    const float* Wo    = (const float*)d_in[7];
    const float* bo    = (const float*)d_in[8];
    const float* gamma = (const float*)d_in[9];
    const float* beta  = (const float*)d_in[10];
    const float* lam   = (const float*)d_in[11];
    float* out = (float*)d_out;

    char* ws = (char*)d_ws;
    const size_t MB = 1u << 20;
    short* Xb  = (short*)(ws + 0);        // 4MB (dead after qkv gemm)
    short* WqT = (short*)(ws + 4 * MB);   // 4MB (dead after qkv gemm)
    short* WkT = (short*)(ws + 8 * MB);   // 4MB
    short* WvT = (short*)(ws + 12 * MB);  // 2MB
    short* WoT = (short*)(ws + 14 * MB);  // 2MB
    short* Qh  = (short*)(ws + 16 * MB);  // 8MB
    short* Kh  = (short*)(ws + 24 * MB);  // 8MB
    short* Vt  = (short*)(ws + 32 * MB);  // 4MB
    short* Oc  = (short*)(ws + 36 * MB);  // 4MB
    float* Yws = (float*)(ws + 0);        // 8MB, aliases Xb+WqT (both dead by then)

    k_convert_x<<<dim3(2048), dim3(256), 0, stream>>>(X, Xb, (S_LEN * EDIM) / 4);
    k_transpose_cvt<<<dim3(4, 32, 16), dim3(32, 8), 0, stream>>>(Wq, WqT, 1024, 128);
    k_transpose_cvt<<<dim3(4, 32, 16), dim3(32, 8), 0, stream>>>(Wk, WkT, 1024, 128);
    k_transpose_cvt<<<dim3(2, 32, 16), dim3(32, 8), 0, stream>>>(Wv, WvT, 1024, 64);
    k_transpose_cvt<<<dim3(32, 32, 1), dim3(32, 8), 0, stream>>>(Wo, WoT, 1024, 1024);
    k_gemm_qkv<<<dim3(640), dim3(512), 0, stream>>>(Xb, WqT, WkT, WvT, bq, bk, bv, Qh, Kh, Vt);
    k_attn<<<dim3(32, 16), dim3(512), 0, stream>>>(Qh, Kh, Vt, lam, Oc);
    k_gemm_out<<<dim3(256), dim3(512), 0, stream>>>(Oc, WoT, bo, Yws);
    k_ln<<<dim3(2048), dim3(256), 0, stream>>>(Yws, gamma, beta, out);
}

// Round 21
// 147.417 us; speedup vs baseline: 1.1004x; 1.1004x over previous
//
#include <hip/hip_runtime.h>

#define S_LEN 2048
#define EDIM  1024
#define HEADS 16
#define DHEAD 64

typedef __attribute__((ext_vector_type(8))) short bf16x8;
typedef __attribute__((ext_vector_type(4))) short short4v;
typedef __attribute__((ext_vector_type(4))) float f32x4;

__device__ inline unsigned short f2bf(float f) {
    unsigned int u = __float_as_uint(f);
    unsigned int r = (u + 0x7FFFu + ((u >> 16) & 1u)) >> 16;
    return (unsigned short)r;
}
__device__ inline float bf2f(unsigned short b) {
    return __uint_as_float(((unsigned int)b) << 16);
}
__device__ inline void load_lds16(const void* g, void* l) {
    __builtin_amdgcn_global_load_lds(
        (const __attribute__((address_space(1))) unsigned int*)g,
        (__attribute__((address_space(3))) unsigned int*)l, 16, 0, 0);
}

// ---------------- fused prep: X fp32->bf16 convert + 4 weight transposes ----------------
// One launch replaces five. Block ranges (block-uniform branch, no divergence):
//   [0,2048)       X convert (256 thr x f32x4)
//   [2048,4096)    Wq  [16][1024][128] -> WqT [16][128][1024]
//   [4096,6144)    Wk  same
//   [6144,7168)    Wv  [16][1024][64]  -> WvT [16][64][1024]
//   [7168,8192)    Wo  [1024][1024]    -> WoT
__global__ __launch_bounds__(256) void k_prep(
        const float* __restrict__ X,  const float* __restrict__ Wq,
        const float* __restrict__ Wk, const float* __restrict__ Wv,
        const float* __restrict__ Wo,
        short* __restrict__ Xb,  short* __restrict__ WqT, short* __restrict__ WkT,
        short* __restrict__ WvT, short* __restrict__ WoT) {
    int bid = blockIdx.x;
    if (bid < 2048) {
        const int i = bid * 256 + threadIdx.x;   // < 524288 = (2048*1024)/4
        f32x4 v = ((const f32x4*)X)[i];
        short4v o;
        o[0] = (short)f2bf(v[0]); o[1] = (short)f2bf(v[1]);
        o[2] = (short)f2bf(v[2]); o[3] = (short)f2bf(v[3]);
        ((short4v*)Xb)[i] = o;
        return;
    }
    bid -= 2048;
    const float* in; short* out; int C, tiles_x;
    if (bid < 2048)      {              in = Wq; out = WqT; C = 128;  tiles_x = 4;  }
    else if (bid < 4096) { bid -= 2048; in = Wk; out = WkT; C = 128;  tiles_x = 4;  }
    else if (bid < 5120) { bid -= 4096; in = Wv; out = WvT; C = 64;   tiles_x = 2;  }
    else                 { bid -= 5120; in = Wo; out = WoT; C = 1024; tiles_x = 32; }
    const int R = 1024;
    const int per_batch = tiles_x * 32;
    const int b = bid / per_batch;
    const int t = bid % per_batch;
    const int c0 = (t % tiles_x) * 32, r0 = (t / tiles_x) * 32;
    in  += (size_t)b * R * C;
    out += (size_t)b * R * C;

    __shared__ float tile[32][33];
    const int tx = threadIdx.x & 31, ty = threadIdx.x >> 5;   // 32 x 8
    #pragma unroll
    for (int yy = 0; yy < 4; ++yy)
        tile[ty + yy * 8][tx] = in[(size_t)(r0 + ty + yy * 8) * C + c0 + tx];
    __syncthreads();
    #pragma unroll
    for (int yy = 0; yy < 4; ++yy)
        out[(size_t)(c0 + ty + yy * 8) * R + r0 + tx] = (short)f2bf(tile[tx][ty + yy * 8]);
}

// ---------------- LDS-staged MFMA GEMM core (m97 structure, NW-wave generalized) ----------------
template<int BM, int BN, int WR, int WC>
__device__ inline void gemm_core(const char* Ag, int ldaB, const char* Bg, int ldbB,
                                 int K, char* sA, char* sB, f32x4* acc) {
    constexpr int NW = WR * WC;
    constexpr int FM = BM / (WR * 16), FN = BN / (WC * 16);
    constexpr int CA = (BM * 128) / (1024 * NW);   // A 1KB-chunks per wave
    constexpr int CB = (BN * 128) / (1024 * NW);   // B 1KB-chunks per wave
    const int lane = threadIdx.x & 63, wave = threadIdx.x >> 6;
    const int rl = lane & 15, g = lane >> 4;
    const int wrow = (wave / WC) * (BM / WR);
    const int wcol = (wave % WC) * (BN / WC);
    const int lr = lane >> 3;                 // row within 8-row chunk
    const int lc = ((lane & 7) ^ lr) << 4;    // inverse-swizzled 16B slot

    for (int t = 0; t < K / 64; ++t) {
        __syncthreads();
        #pragma unroll
        for (int i = 0; i < CA; ++i) {
            const int c = i * NW + wave;      // chunk c covers rows [8c, 8c+8)
            load_lds16(Ag + (size_t)(c * 8 + lr) * ldaB + t * 128 + lc, sA + c * 1024);
        }
        #pragma unroll
        for (int i = 0; i < CB; ++i) {
            const int c = i * NW + wave;
            load_lds16(Bg + (size_t)(c * 8 + lr) * ldbB + t * 128 + lc, sB + c * 1024);
        }
        __syncthreads();
        #pragma unroll
        for (int kk = 0; kk < 2; ++kk) {
            bf16x8 af[FM], bf[FN];
            #pragma unroll
            for (int f = 0; f < FM; ++f) {
                const int r = wrow + f * 16 + rl;
                af[f] = *(const bf16x8*)(sA + r * 128 + (((kk * 4 + g) ^ (r & 7)) << 4));
            }
            #pragma unroll
            for (int j = 0; j < FN; ++j) {
                const int r = wcol + j * 16 + rl;
                bf[j] = *(const bf16x8*)(sB + r * 128 + (((kk * 4 + g) ^ (r & 7)) << 4));
            }
            #pragma unroll
            for (int f = 0; f < FM; ++f)
                #pragma unroll
                for (int j = 0; j < FN; ++j)
                    acc[f * FN + j] = __builtin_amdgcn_mfma_f32_16x16x32_bf16(af[f], bf[j], acc[f * FN + j], 0, 0, 0);
        }
    }
}

// ---------------- QKV projection GEMM: 128x128 tiles, 8 waves (2M x 4N) ----------------
__global__ __launch_bounds__(512) void k_gemm_qkv(
        const short* __restrict__ Xb,
        const short* __restrict__ WqT, const short* __restrict__ WkT, const short* __restrict__ WvT,
        const float* __restrict__ bq, const float* __restrict__ bk, const float* __restrict__ bv,
        short* __restrict__ Qh, short* __restrict__ Kh, short* __restrict__ Vt) {
    __shared__ __align__(16) char sA[16384], sB[16384];
    int id = blockIdx.x;
    id = (id & 7) * 80 + (id >> 3);           // XCD-contiguous chunks
    const int mbase = (id % 16) * 128;
    const int y = id / 16;

    const short* Bt; const float* bias; int nbase; int which;
    if (y < 16)      { which = 0; Bt = WqT; bias = bq; nbase = y * 128; }
    else if (y < 32) { which = 1; Bt = WkT; bias = bk; nbase = (y - 16) * 128; }
    else             { which = 2; Bt = WvT; bias = bv; nbase = (y - 32) * 128; }

    f32x4 acc[8];
    #pragma unroll
    for (int i = 0; i < 8; ++i) acc[i] = (f32x4){0.f, 0.f, 0.f, 0.f};

    gemm_core<128, 128, 2, 4>((const char*)Xb + (size_t)mbase * 2048, 2048,
                              (const char*)Bt + (size_t)nbase * 2048, 2048,
                              EDIM, sA, sB, acc);

    const int lane = threadIdx.x & 63, wave = threadIdx.x >> 6;
    const int wr = (wave >> 2) * 64, wc = (wave & 3) * 32;
    const int rl = lane & 15, g = lane >> 4;
    const float qscale = 0.125f * 1.44269504088896f;
    #pragma unroll
    for (int i = 0; i < 4; ++i)
        #pragma unroll
        for (int j = 0; j < 2; ++j)
            #pragma unroll
            for (int jj = 0; jj < 4; ++jj) {
                int s = mbase + wr + i * 16 + g * 4 + jj;
                int n = nbase + wc + j * 16 + rl;
                float v = acc[i * 2 + j][jj] + bias[n];
                if (which == 0) v *= qscale;
                short b16 = (short)f2bf(v);
                if (which == 0)      Qh[((size_t)(n >> 7) * S_LEN + s) * 128 + (n & 127)] = b16;
                else if (which == 1) Kh[((size_t)(n >> 7) * S_LEN + s) * 128 + (n & 127)] = b16;
                else                 Vt[(size_t)n * S_LEN + s] = b16;
            }
}

// ---------------- differential flash attention, v10 (best verified: 81us) ----------------
// KVBLK=32, fixed-shift softmax (MFIX), row sums via ones-MFMA, 2-way in-block
// kv-split, dbuf K prefetch, V from global, P packed-pair [16 q][128B] rows.
__global__ __launch_bounds__(512, 4) void k_attn(
        const short* __restrict__ Qh, const short* __restrict__ Kh,
        const short* __restrict__ Vt, const float* __restrict__ lam_p,
        short* __restrict__ Ocat) {
    __shared__ __align__(16) char smem[49152];

    const int lane = threadIdx.x & 63, wave = threadIdx.x >> 6;
    const int rl = lane & 15, g = lane >> 4;
    const int qw = wave & 3, kvg = wave >> 2;
    const int h = blockIdx.y;
    const int qbase = blockIdx.x * 64 + qw * 16;
    const int kx = rl & 7;              // K-row swizzle key (256B rows)
    const int swz = (rl & 7) << 4;      // P-row swizzle key (128B rows)
    const float MFIX = 6.0f;            // fixed exp2-domain shift

    char* Kg0 = smem + kvg * 16384;            // 2 bufs x 8KB: [32 kv][256B]
    char* Pw  = smem + 32768 + wave * 2048;    // [16 q][128B] = {p0 64B | p1 64B} swizzled

    const char* Kgb = (const char*)(Kh + (size_t)h * S_LEN * 128);
    const char* Vgb = (const char*)(Vt + (size_t)h * DHEAD * S_LEN);
    const short* Qp = Qh + (size_t)h * S_LEN * 128;

    const int kc0 = qw * 2, kc1 = qw * 2 + 1;
    const int kofs0 = (lane >> 4) * 256 + (((lane & 15) ^ (lane >> 4)) << 4);
    const int kofs1 = (lane >> 4) * 256 + (((lane & 15) ^ ((lane >> 4) + 4)) << 4);

    auto STAGE = [&](int b, int it) {
        const size_t kv0 = (size_t)(kvg * 1024 + it * 32);
        char* kb = Kg0 + b * 8192;
        load_lds16(Kgb + (kv0 + (size_t)kc0 * 4) * 256 + kofs0, kb + kc0 * 1024);
        load_lds16(Kgb + (kv0 + (size_t)kc1 * 4) * 256 + kofs1, kb + kc1 * 1024);
    };

    STAGE(0, 0);

    bf16x8 qf[2][2];
    #pragma unroll
    for (int p = 0; p < 2; ++p)
        #pragma unroll
        for (int kc = 0; kc < 2; ++kc)
            qf[p][kc] = *(const bf16x8*)&Qp[(size_t)(qbase + rl) * 128 + p * 64 + kc * 32 + g * 8];

    bf16x8 ones;
    #pragma unroll
    for (int i = 0; i < 8; ++i) ones[i] = (short)0x3F80;   // bf16 1.0

    f32x4 acc[2][4], accL[2];
    #pragma unroll
    for (int p = 0; p < 2; ++p) {
        #pragma unroll
        for (int t = 0; t < 4; ++t) acc[p][t] = (f32x4){0.f, 0.f, 0.f, 0.f};
        accL[p] = (f32x4){0.f, 0.f, 0.f, 0.f};
    }

    __syncthreads();   // prologue stage drained

    const int NIT = 1024 / 32;
    for (int it = 0; it < NIT; ++it) {
        const int cur = it & 1;
        if (it + 1 < NIT) STAGE(cur ^ 1, it + 1);   // issue-early K prefetch
        const char* kb = Kg0 + cur * 8192;
        const size_t kv0 = (size_t)(kvg * 1024 + it * 32);

        // ---- V fragments straight from global (no in-iter deps -> hoistable) ----
        bf16x8 vf[4];
        #pragma unroll
        for (int t = 0; t < 4; ++t)
            vf[t] = *(const bf16x8*)(Vgb + (size_t)(t * 16 + rl) * 4096 + (kv0 + g * 8) * 2);

        #pragma unroll
        for (int p = 0; p < 2; ++p) {
            // ---- QK^T (swapped: mfma(K,Q)); Q pre-scaled -> exp2 domain ----
            f32x4 sc[2];
            #pragma unroll
            for (int t = 0; t < 2; ++t) {
                f32x4 z = (f32x4){0.f, 0.f, 0.f, 0.f};
                #pragma unroll
                for (int kc = 0; kc < 2; ++kc) {
                    bf16x8 kf = *(const bf16x8*)(kb + t * 4096 + rl * 256 + (((p * 8 + kc * 4 + g) ^ kx) << 4));
                    z = __builtin_amdgcn_mfma_f32_16x16x32_bf16(kf, qf[p][kc], z, 0, 0, 0);
                }
                sc[t] = z;
            }

            // ---- P = exp2(S - MFIX): packed cvt_pk pair writes into 128B rows ----
            #pragma unroll
            for (int t = 0; t < 2; ++t) {
                #pragma unroll
                for (int jjp = 0; jjp < 4; jjp += 2) {
                    float e0 = exp2f(sc[t][jjp]     - MFIX);
                    float e1 = exp2f(sc[t][jjp + 1] - MFIX);
                    unsigned u;
                    asm("v_cvt_pk_bf16_f32 %0, %1, %2" : "=v"(u) : "v"(e0), "v"(e1));
                    *(unsigned*)(Pw + rl * 128 + ((p * 64 + (t * 16 + g * 4 + jjp) * 2) ^ swz)) = u;
                }
            }

            // ---- O += P @ V; l += P @ ones (row sums on the matrix pipe) ----
            bf16x8 pa = *(const bf16x8*)(Pw + rl * 128 + ((p * 64 + g * 16) ^ swz));
            accL[p] = __builtin_amdgcn_mfma_f32_16x16x32_bf16(pa, ones, accL[p], 0, 0, 0);
            #pragma unroll
            for (int t = 0; t < 4; ++t)
                acc[p][t] = __builtin_amdgcn_mfma_f32_16x16x32_bf16(pa, vf[t], acc[p][t], 0, 0, 0);
        }
        __syncthreads();   // drains this iter's K prefetch; next buffer ready
    }

    // ---- exchange partials through LDS (staging/P regions dead) ----
    {
        unsigned short* Xw = (unsigned short*)(smem + wave * 4096);  // [2][16][64] bf16
        float* ML = (float*)(smem + 32768);                          // [8w][2p][16 q] l only
        #pragma unroll
        for (int p = 0; p < 2; ++p) {
            #pragma unroll
            for (int t = 0; t < 4; ++t)
                #pragma unroll
                for (int jj = 0; jj < 4; ++jj)
                    Xw[p * 1024 + (g * 4 + jj) * 64 + t * 16 + rl] = f2bf(acc[p][t][jj]);
            if (rl == 0) {
                #pragma unroll
                for (int jj = 0; jj < 4; ++jj)
                    ML[(wave * 2 + p) * 16 + g * 4 + jj] = accL[p][jj];
            }
        }
    }
    __syncthreads();

    // ---- combine the 2 kv-group partials; thread -> (q = tid>>3, d0 = (tid&7)*8) ----
    {
        const int q = threadIdx.x >> 3, d0 = (threadIdx.x & 7) * 8;
        const int q15 = q & 15, wa = q >> 4, wb = (q >> 4) + 4;
        const float* ML = (const float*)(smem + 32768);
        const float lam = lam_p[0];
        float res[2][8];
        float invL[2];
        #pragma unroll
        for (int p = 0; p < 2; ++p) {
            float la = ML[(wa * 2 + p) * 16 + q15];
            float lb = ML[(wb * 2 + p) * 16 + q15];
            invL[p] = 1.0f / (la + lb);
            const unsigned short* xa = (const unsigned short*)(smem + wa * 4096 + p * 2048 + q15 * 128 + d0 * 2);
            const unsigned short* xb = (const unsigned short*)(smem + wb * 4096 + p * 2048 + q15 * 128 + d0 * 2);
            #pragma unroll
            for (int k = 0; k < 8; ++k)
                res[p][k] = bf2f(xa[k]) + bf2f(xb[k]);
        }
        bf16x8 ov;
        #pragma unroll
        for (int k = 0; k < 8; ++k)
            ov[k] = (short)f2bf(res[0][k] * invL[0] - lam * res[1][k] * invL[1]);
        *(bf16x8*)&Ocat[(size_t)(blockIdx.x * 64 + q) * 1024 + h * 64 + d0] = ov;
    }
}

// ---------------- output projection GEMM: 64x128 tiles, 8 waves (2M x 4N) ----------------
__global__ __launch_bounds__(512) void k_gemm_out(
        const short* __restrict__ Ocat, const short* __restrict__ WoT,
        const float* __restrict__ bo, float* __restrict__ Yws) {
    __shared__ __align__(16) char sA[8192], sB[16384];
    int id = blockIdx.x;
    id = (id & 7) * 32 + (id >> 3);
    const int mbase = (id % 32) * 64;
    const int nbase = (id / 32) * 128;

    f32x4 acc[4];
    #pragma unroll
    for (int i = 0; i < 4; ++i) acc[i] = (f32x4){0.f, 0.f, 0.f, 0.f};

    gemm_core<64, 128, 2, 4>((const char*)Ocat + (size_t)mbase * 2048, 2048,
                             (const char*)WoT + (size_t)nbase * 2048, 2048,
                             1024, sA, sB, acc);

    const int lane = threadIdx.x & 63, wave = threadIdx.x >> 6;
    const int wr = (wave >> 2) * 32, wc = (wave & 3) * 32;
    const int rl = lane & 15, g = lane >> 4;
    #pragma unroll
    for (int f = 0; f < 2; ++f)
        #pragma unroll
        for (int j = 0; j < 2; ++j)
            #pragma unroll
            for (int jj = 0; jj < 4; ++jj) {
                int s = mbase + wr + f * 16 + g * 4 + jj;
                int e = nbase + wc + j * 16 + rl;
                Yws[(size_t)s * 1024 + e] = acc[f * 2 + j][jj] + bo[e];
            }
}

// ---------------- LayerNorm + final scale ----------------
__global__ __launch_bounds__(256) void k_ln(
        const float* __restrict__ Yws, const float* __restrict__ gamma,
        const float* __restrict__ beta, float* __restrict__ out) {
    const int s = blockIdx.x;
    const int tid = threadIdx.x;
    f32x4 y = ((const f32x4*)(Yws + (size_t)s * 1024))[tid];
    float sum = y[0] + y[1] + y[2] + y[3];
    float sq  = y[0]*y[0] + y[1]*y[1] + y[2]*y[2] + y[3]*y[3];
    #pragma unroll
    for (int off = 1; off < 64; off <<= 1) {
        sum += __shfl_xor(sum, off, 64);
        sq  += __shfl_xor(sq,  off, 64);
    }
    __shared__ float ls[2][4];
    const int wave = tid >> 6, lane = tid & 63;
    if (lane == 0) { ls[0][wave] = sum; ls[1][wave] = sq; }
    __syncthreads();
    sum = ls[0][0] + ls[0][1] + ls[0][2] + ls[0][3];
    sq  = ls[1][0] + ls[1][1] + ls[1][2] + ls[1][3];
    const float mu = sum * (1.f / 1024.f);
    const float var = sq * (1.f / 1024.f) - mu * mu;
    const float rstd = rsqrtf(var + 1e-5f);
    f32x4 gg = ((const f32x4*)gamma)[tid];
    f32x4 bb = ((const f32x4*)beta)[tid];
    f32x4 o;
    #pragma unroll
    for (int k = 0; k < 4; ++k)
        o[k] = ((y[k] - mu) * rstd * gg[k] + bb[k]) * 0.2f;
    ((f32x4*)(out + (size_t)s * 1024))[tid] = o;
}

extern "C" void kernel_launch(void* const* d_in, const int* in_sizes, int n_in,
                              void* d_out, int out_size, void* d_ws, size_t ws_size,
                              hipStream_t stream) {
    const float* X     = (const float*)d_in[0];
    const float* Wq    = (const float*)d_in[1];
    const float* bq    = (const float*)d_in[2];
    const float* Wk    = (const float*)d_in[3];
    const float* bk    = (const float*)d_in[4];
    const float* Wv    = (const float*)d_in[5];
    const float* bv    = (const float*)d_in[6];
    const float* Wo    = (const float*)d_in[7];
    const float* bo    = (const float*)d_in[8];
    const float* gamma = (const float*)d_in[9];
    const float* beta  = (const float*)d_in[10];
    const float* lam   = (const float*)d_in[11];
    float* out = (float*)d_out;

    char* ws = (char*)d_ws;
    const size_t MB = 1u << 20;
    short* Xb  = (short*)(ws + 0);        // 4MB (dead after qkv gemm)
    short* WqT = (short*)(ws + 4 * MB);   // 4MB (dead after qkv gemm)
    short* WkT = (short*)(ws + 8 * MB);   // 4MB
    short* WvT = (short*)(ws + 12 * MB);  // 2MB
    short* WoT = (short*)(ws + 14 * MB);  // 2MB
    short* Qh  = (short*)(ws + 16 * MB);  // 8MB
    short* Kh  = (short*)(ws + 24 * MB);  // 8MB
    short* Vt  = (short*)(ws + 32 * MB);  // 4MB
    short* Oc  = (short*)(ws + 36 * MB);  // 4MB
    float* Yws = (float*)(ws + 0);        // 8MB, aliases Xb+WqT (both dead by then)

    k_prep<<<dim3(8192), dim3(256), 0, stream>>>(X, Wq, Wk, Wv, Wo, Xb, WqT, WkT, WvT, WoT);
    k_gemm_qkv<<<dim3(640), dim3(512), 0, stream>>>(Xb, WqT, WkT, WvT, bq, bk, bv, Qh, Kh, Vt);
    k_attn<<<dim3(32, 16), dim3(512), 0, stream>>>(Qh, Kh, Vt, lam, Oc);
    k_gemm_out<<<dim3(256), dim3(512), 0, stream>>>(Oc, WoT, bo, Yws);
    k_ln<<<dim3(2048), dim3(256), 0, stream>>>(Yws, gamma, beta, out);
}